// Round 3
// baseline (2082.289 us; speedup 1.0000x reference)
//
#include <hip/hip_runtime.h>
#include <math.h>

#define TT 2048

typedef __attribute__((ext_vector_type(8))) short bfrag;   // 8 bf16 in 4 VGPRs
typedef __attribute__((ext_vector_type(4))) float facc;    // 4 fp32 acc

#define NEG_BIG (-1.0e30f)

typedef __attribute__((address_space(1))) const void gas_void;
typedef __attribute__((address_space(3))) void las_void;

__device__ __forceinline__ void gl_lds16(const void* g, void* l) {
    __builtin_amdgcn_global_load_lds((gas_void*)g, (las_void*)l, 16, 0, 0);
}

__device__ __forceinline__ unsigned short f2b(float f) {
    union { float f; unsigned int i; } v; v.f = f;
    unsigned int b = v.i;
    return (unsigned short)((b + 0x7FFFu + ((b >> 16) & 1u)) >> 16);  // RNE
}
__device__ __forceinline__ float b2f(unsigned short s) {
    union { unsigned int i; float f; } u; u.i = ((unsigned int)s) << 16; return u.f;
}
__device__ __forceinline__ void cvt8_f32(const float* __restrict__ p, unsigned short* d) {
    float4 lo = *(const float4*)p, hi = *(const float4*)(p + 4);
    d[0] = f2b(lo.x); d[1] = f2b(lo.y); d[2] = f2b(lo.z); d[3] = f2b(lo.w);
    d[4] = f2b(hi.x); d[5] = f2b(hi.y); d[6] = f2b(hi.z); d[7] = f2b(hi.w);
}

// ---------------------------------------------------------------------------
// fp32 -> bf16 flat convert (n8 = count of 8-element chunks)
// ---------------------------------------------------------------------------
__global__ __launch_bounds__(256) void k_cvt(const float* __restrict__ in,
                                             unsigned short* __restrict__ out, int n8) {
    int c = blockIdx.x * 256 + threadIdx.x;
    if (c < n8) {
        unsigned short t[8];
        cvt8_f32(in + (size_t)c * 8, t);
        *(uint4*)(out + (size_t)c * 8) = *(const uint4*)t;
    }
}

// ---------------------------------------------------------------------------
// Weight transpose+convert: W (2048 x N fp32, row-major) -> WT (N x 2048 bf16)
// ---------------------------------------------------------------------------
__global__ __launch_bounds__(256) void k_wt(const float* __restrict__ W,
                                            unsigned short* __restrict__ WT, int N) {
    __shared__ alignas(16) unsigned short tile[64][72];
    int r0 = blockIdx.y * 64, c0 = blockIdx.x * 64;
    int tid = threadIdx.x;
    for (int i = 0; i < 2; ++i) {
        int c = tid + i * 256;
        int row = c >> 3, c8 = (c & 7) * 8;
        unsigned short t[8];
        cvt8_f32(W + (size_t)(r0 + row) * N + c0 + c8, t);
        *(uint4*)&tile[row][c8] = *(const uint4*)t;
    }
    __syncthreads();
    for (int i = 0; i < 2; ++i) {
        int c = tid + i * 256;
        int col = c >> 3, r8 = (c & 7) * 8;
        unsigned short t[8];
        for (int j = 0; j < 8; ++j) t[j] = tile[r8 + j][col];
        *(uint4*)(WT + (size_t)(c0 + col) * 2048 + r0 + r8) = *(const uint4*)t;
    }
}

// ---------------------------------------------------------------------------
// V transpose: QKV (8192 x 3072 bf16, V = cols 2560..3071) -> VbT (512 x 8192)
// ---------------------------------------------------------------------------
__global__ __launch_bounds__(256) void k_vt(const unsigned short* __restrict__ QKV,
                                            unsigned short* __restrict__ VbT) {
    __shared__ alignas(16) unsigned short tile[64][72];
    int r0 = blockIdx.y * 64, c0 = blockIdx.x * 64;
    int tid = threadIdx.x;
    for (int i = 0; i < 2; ++i) {
        int c = tid + i * 256;
        int row = c >> 3, c8 = (c & 7) * 8;
        *(uint4*)&tile[row][c8] =
            *(const uint4*)(QKV + (size_t)(r0 + row) * 3072 + 2560 + c0 + c8);
    }
    __syncthreads();
    for (int i = 0; i < 2; ++i) {
        int c = tid + i * 256;
        int col = c >> 3, r8 = (c & 7) * 8;
        unsigned short t[8];
        for (int j = 0; j < 8; ++j) t[j] = tile[r8 + j][col];
        *(uint4*)(VbT + (size_t)(c0 + col) * 8192 + r0 + r8) = *(const uint4*)t;
    }
}

// ---------------------------------------------------------------------------
// m97-style GEMM (proven): C (MxN) = A (MxK bf16) @ Bt^T (Bt: NxK bf16).
// 128x128 tile, BK=32, global_load_lds width=16, XOR chunk swizzle.
// ropeF=1: apply RoPE in the bf16 epilogue to cols < 2560 (Q heads 0..15 at
// cols h*128, K heads at 2048+kvh*128). Bit-identical to the old separate
// k_rope pass: reads the already-rounded bf16 from LDS, f32 math, f2b store.
// Partner element (d xor 64) is in the same 128-wide tile row.
// ---------------------------------------------------------------------------
__global__ __launch_bounds__(256) void k_gemm_bt(const unsigned short* __restrict__ A,
                                                 const unsigned short* __restrict__ Bt,
                                                 void* __restrict__ Cmat,
                                                 int M, int N, int K, int outF,
                                                 const int* __restrict__ posPtr, int ropeF) {
    __shared__ union SM {
        struct { unsigned short A[128][32]; unsigned short B[128][32]; } s;  // 16 KB
        unsigned short ct[32][136];
        float          ctf[32][136];
    } sm;
    int tid = threadIdx.x;
    int w = tid >> 6, lane = tid & 63, quad = lane >> 4, l15 = lane & 15;
    int m0 = blockIdx.y * 128, n0 = blockIdx.x * 128;
    int wm = (w >> 1) * 64, wn = (w & 1) * 64;
    int posv = ropeF ? *posPtr : 0;

    int srow   = lane >> 2;                       // 0..15 row within 16-row chunk
    int schunk = (lane & 3) ^ ((lane >> 3) & 3);  // XOR-swizzled 16B chunk
    int rslot = (quad ^ ((l15 >> 1) & 3)) * 8;

    facc acc[4][4];
    for (int mi = 0; mi < 4; ++mi)
        for (int ni = 0; ni < 4; ++ni)
            for (int r = 0; r < 4; ++r) acc[mi][ni][r] = 0.f;

    for (int k0 = 0; k0 < K; k0 += 32) {
        for (int j = 0; j < 2; ++j) {
            int row = w * 32 + j * 16 + srow;     // 0..127
            gl_lds16(A  + (size_t)(m0 + row) * K + k0 + schunk * 8, &sm.s.A[w * 32 + j * 16][0]);
            gl_lds16(Bt + (size_t)(n0 + row) * K + k0 + schunk * 8, &sm.s.B[w * 32 + j * 16][0]);
        }
        __syncthreads();
        bfrag af[4], bf[4];
        for (int mi = 0; mi < 4; ++mi) af[mi] = *(const bfrag*)&sm.s.A[wm + mi * 16 + l15][rslot];
        for (int ni = 0; ni < 4; ++ni) bf[ni] = *(const bfrag*)&sm.s.B[wn + ni * 16 + l15][rslot];
        for (int mi = 0; mi < 4; ++mi)
            for (int ni = 0; ni < 4; ++ni)
                acc[mi][ni] = __builtin_amdgcn_mfma_f32_16x16x32_bf16(af[mi], bf[ni], acc[mi][ni], 0, 0, 0);
        __syncthreads();
    }

    for (int t = 0; t < 4; ++t) {
        __syncthreads();
        for (int ni = 0; ni < 4; ++ni)
            for (int r = 0; r < 4; ++r) {
                int lr = (w >> 1) * 16 + quad * 4 + r;
                int lc = wn + ni * 16 + l15;
                if (outF) sm.ctf[lr][lc] = acc[t][ni][r];
                else      sm.ct [lr][lc] = f2b(acc[t][ni][r]);
            }
        __syncthreads();
        if (outF) {
            for (int i = 0; i < 4; ++i) {
                int cc = tid + i * 256;
                int lr = cc >> 5, c4 = (cc & 31) * 4;
                int grow = m0 + (lr >> 4) * 64 + t * 16 + (lr & 15);
                *(float4*)((float*)Cmat + (size_t)grow * N + n0 + c4) =
                    *(const float4*)&sm.ctf[lr][c4];
            }
        } else {
            for (int i = 0; i < 2; ++i) {
                int cc = tid + i * 256;
                int lr = cc >> 4, c8 = (cc & 15) * 8;
                int grow = m0 + (lr >> 4) * 64 + t * 16 + (lr & 15);
                uint4 val = *(const uint4*)&sm.ct[lr][c8];
                if (ropeF && (n0 + c8) < 2560) {
                    unsigned short prt[8];
                    *(uint4*)prt = *(const uint4*)&sm.ct[lr][c8 ^ 64];
                    unsigned short* sp = (unsigned short*)&val;
                    float pp = (float)(posv + (grow & (TT - 1)));
                    int hi = (n0 + c8) & 64;          // 0 => lower half (x1), 64 => upper (x2)
                    int dbase = (n0 + c8) & 63;       // multiple of 8
                    for (int j = 0; j < 8; ++j) {
                        float a = b2f(sp[j]), bq = b2f(prt[j]);
                        int i1 = (dbase + j) >> 1;
                        float th = pp * exp2f(-(float)(i1 + (hi ? 32 : 0)) * 0.20762050595278f);
                        float cth = cosf(th), sth = sinf(th);
                        float ov = hi ? (a * cth + bq * sth) : (a * cth - bq * sth);
                        sp[j] = f2b(ov);
                    }
                }
                *(uint4*)((unsigned short*)Cmat + (size_t)grow * N + n0 + c8) = val;
            }
        }
    }
}

// ---------------------------------------------------------------------------
// Flash attention, causal, GQA (16 q / 4 kv heads). 512 threads, QBLK=128,
// paired q-tiles (i, 15-i) for perfect balance; double-buffered K/V LDS,
// one barrier per K-step, register prefetch issued post-barrier.
// VALU cuts: per-wave inactive-tile skip (fully-masked tiles do barriers
// only); wave-uniform interior-tile fast path (no mask cndmasks); T13
// defer-max THR=8 (rescale ~never fires after tile 0; exp(-big)=0 handles
// masked lanes exactly as the explicit zero did).
// ---------------------------------------------------------------------------
__device__ __forceinline__ void flash_pass(
    int qbase, int b, int h, int kvh,
    const unsigned short* __restrict__ QKV,
    const unsigned short* __restrict__ VbT,
    unsigned short* __restrict__ att,
    unsigned short (&Ks)[2][32][136],
    unsigned short (&Vt)[2][128][40],
    unsigned short (&Pt)[8][16][40]) {

    int tid = threadIdx.x;
    int w = tid >> 6, lane = tid & 63, quad = lane >> 4, l15 = lane & 15;

    bfrag qf[4];
    {
        size_t qrow = (size_t)(b * TT + qbase + w * 16 + l15);
        for (int kc = 0; kc < 4; ++kc)
            qf[kc] = *(const bfrag*)(QKV + qrow * 3072 + h * 128 + kc * 32 + quad * 8);
    }

    float mrow[4], lrow[4];
    facc o[8];
    for (int r = 0; r < 4; ++r) { mrow[r] = NEG_BIG; lrow[r] = 0.f; }
    for (int nb2 = 0; nb2 < 8; ++nb2)
        for (int r = 0; r < 4; ++r) o[nb2][r] = 0.f;

    int krow = tid >> 4, d8 = (tid & 15) * 8;   // K: row 0..31, 16B chunk
    int vd = tid >> 2, tc = (tid & 3) * 8;      // V: d 0..127, 8 t-cols
    const unsigned short* Kg = QKV + (size_t)(b * TT) * 3072 + 2048 + kvh * 128;
    const unsigned short* Vg = VbT + (size_t)(kvh * 128 + vd) * 8192 + b * TT;

    const float sc = 0.08838834764831845f;   // 1/sqrt(128)
    int kmax = qbase + 128;
    int nt = kmax >> 5;
    int qgmin = qbase + w * 16;              // smallest q-row this wave owns

    uint4 rk = *(const uint4*)(Kg + (size_t)krow * 3072 + d8);
    uint4 rv = *(const uint4*)(Vg + tc);

    for (int t = 0; t < nt; ++t) {
        int cur = t & 1;
        int k0 = t * 32;
        *(uint4*)&Ks[cur][krow][d8] = rk;
        *(uint4*)&Vt[cur][vd][tc]   = rv;
        __syncthreads();

        if (t + 1 < nt) {
            int k0n = k0 + 32;
            rk = *(const uint4*)(Kg + (size_t)(k0n + krow) * 3072 + d8);
            rv = *(const uint4*)(Vg + k0n + tc);
        }

        // tiles entirely above this wave's rows contribute nothing: skip
        // compute (barriers at loop top stay uniform).
        if (k0 > qgmin + 15) continue;

        facc s[2];
        for (int nb = 0; nb < 2; ++nb) {
            for (int r = 0; r < 4; ++r) s[nb][r] = 0.f;
            for (int kc = 0; kc < 4; ++kc) {
                bfrag kf = *(const bfrag*)&Ks[cur][nb * 16 + l15][kc * 32 + quad * 8];
                s[nb] = __builtin_amdgcn_mfma_f32_16x16x32_bf16(qf[kc], kf, s[nb], 0, 0, 0);
            }
        }

        bool fullT = (k0 + 31) <= qgmin;     // wave-uniform: no masking needed
        float alpha[4];
        int growAny = 0;
        for (int r = 0; r < 4; ++r) {
            float v0, v1;
            if (fullT) {
                v0 = s[0][r] * sc;
                v1 = s[1][r] * sc;
            } else {
                int qg = qgmin + quad * 4 + r;
                v0 = (k0 + l15 > qg)      ? NEG_BIG : s[0][r] * sc;
                v1 = (k0 + 16 + l15 > qg) ? NEG_BIG : s[1][r] * sc;
            }
            float mx = fmaxf(v0, v1);
            for (int off = 1; off < 16; off <<= 1) mx = fmaxf(mx, __shfl_xor(mx, off, 64));
            bool need = (mx > mrow[r] + 8.f);     // T13 defer-max, THR=8
            float mnew = need ? mx : mrow[r];
            growAny |= need;
            alpha[r] = need ? __expf(mrow[r] - mnew) : 1.f;
            float p0 = __expf(v0 - mnew);         // exp(-huge)=0 for masked lanes
            float p1 = __expf(v1 - mnew);
            float psum = p0 + p1;
            for (int off = 1; off < 16; off <<= 1) psum += __shfl_xor(psum, off, 64);
            lrow[r] = lrow[r] * alpha[r] + psum;
            mrow[r] = mnew;
            Pt[w][quad * 4 + r][l15]      = f2b(p0);
            Pt[w][quad * 4 + r][16 + l15] = f2b(p1);
        }
        if (__any(growAny)) {
            for (int nb2 = 0; nb2 < 8; ++nb2)
                for (int r = 0; r < 4; ++r) o[nb2][r] *= alpha[r];
        }

        asm volatile("s_waitcnt lgkmcnt(0)" ::: "memory");   // wave-local RAW on Pt[w]
        bfrag pf = *(const bfrag*)&Pt[w][l15][quad * 8];
        for (int nb2 = 0; nb2 < 8; ++nb2) {
            bfrag vf = *(const bfrag*)&Vt[cur][nb2 * 16 + l15][quad * 8];
            o[nb2] = __builtin_amdgcn_mfma_f32_16x16x32_bf16(pf, vf, o[nb2], 0, 0, 0);
        }
    }

    for (int nb2 = 0; nb2 < 8; ++nb2)
        for (int r = 0; r < 4; ++r) {
            int qg = qbase + w * 16 + quad * 4 + r;
            att[(size_t)(b * TT + qg) * 2048 + h * 128 + nb2 * 16 + l15] =
                f2b(o[nb2][r] / lrow[r]);
        }
}

__global__ __launch_bounds__(512, 4) void k_flash(const unsigned short* __restrict__ QKV,
                                                  const unsigned short* __restrict__ VbT,
                                                  unsigned short* __restrict__ att) {
    __shared__ alignas(16) unsigned short Ks[2][32][136];
    __shared__ alignas(16) unsigned short Vt[2][128][40];
    __shared__ alignas(16) unsigned short Pt[8][16][40];
    int bh = blockIdx.y;
    int b = bh >> 4, h = bh & 15;
    int kvh = h >> 2;
    int i = blockIdx.x;

    flash_pass(i * 128, b, h, kvh, QKV, VbT, att, Ks, Vt, Pt);
    __syncthreads();
    flash_pass((15 - i) * 128, b, h, kvh, QKV, VbT, att, Ks, Vt, Pt);
}

// ---------------------------------------------------------------------------
extern "C" void kernel_launch(void* const* d_in, const int* in_sizes, int n_in,
                              void* d_out, int out_size, void* d_ws, size_t ws_size,
                              hipStream_t stream) {
    const float* x  = (const float*)d_in[0];
    const float* Wq = (const float*)d_in[1];
    const float* Wk = (const float*)d_in[2];
    const float* Wv = (const float*)d_in[3];
    const float* Wo = (const float*)d_in[4];
    const int* pos  = (const int*)d_in[5];

    char* ws = (char*)d_ws;
    unsigned short* xb   = (unsigned short*)(ws + 0);          // 32 MB (8192x2048); reused as att out
    unsigned short* QKV  = (unsigned short*)(ws + 33554432);   // 48 MB (8192x3072)
    unsigned short* VbT  = (unsigned short*)(ws + 83886080);   //  8 MB (512x8192)
    unsigned short* WqT  = (unsigned short*)(ws + 92274688);   //  8 MB (2048x2048)
    unsigned short* WkvT = (unsigned short*)(ws + 100663296);  //  4 MB (1024x2048) -- contiguous with WqT
    unsigned short* WoT  = (unsigned short*)(ws + 104857600);  //  8 MB -> 108 MB total

    // bf16 conversion + weight transposes (WqT|WkvT form one contiguous 3072x2048 Bt)
    k_cvt<<<8192, 256, 0, stream>>>(x, xb, 2097152);
    k_wt<<<dim3(32, 32), 256, 0, stream>>>(Wq, WqT, 2048);
    k_wt<<<dim3(8, 32),  256, 0, stream>>>(Wk, WkvT, 512);
    k_wt<<<dim3(8, 32),  256, 0, stream>>>(Wv, WkvT + (size_t)512 * 2048, 512);
    k_wt<<<dim3(32, 32), 256, 0, stream>>>(Wo, WoT, 2048);

    // fused Q|K|V projection with fused RoPE in epilogue (Q cols 0..2047,
    // K cols 2048..2559; V untouched)
    k_gemm_bt<<<dim3(24, 64), 256, 0, stream>>>(xb, WqT, QKV, 8192, 3072, 2048, 0, pos, 1);

    // V transpose for flash B-frag staging
    k_vt<<<dim3(8, 128), 256, 0, stream>>>(QKV, VbT);

    // causal GQA flash attention -> xb (x no longer needed)
    k_flash<<<dim3(8, 64), 512, 0, stream>>>(QKV, VbT, xb);

    // output projection -> fp32 d_out
    k_gemm_bt<<<dim3(16, 64), 256, 0, stream>>>(xb, WoT, d_out, 8192, 2048, 2048, 1, nullptr, 0);
}

// Round 4
// 778.289 us; speedup vs baseline: 2.6755x; 2.6755x over previous
//
#include <hip/hip_runtime.h>
#include <math.h>

#define TT 2048

typedef __attribute__((ext_vector_type(8))) short bfrag;   // 8 bf16 in 4 VGPRs
typedef __attribute__((ext_vector_type(4))) float facc;    // 4 fp32 acc

#define NEG_BIG (-1.0e30f)

typedef __attribute__((address_space(1))) const void gas_void;
typedef __attribute__((address_space(3))) void las_void;

__device__ __forceinline__ void gl_lds16(const void* g, void* l) {
    __builtin_amdgcn_global_load_lds((gas_void*)g, (las_void*)l, 16, 0, 0);
}

__device__ __forceinline__ unsigned short f2b(float f) {
    union { float f; unsigned int i; } v; v.f = f;
    unsigned int b = v.i;
    return (unsigned short)((b + 0x7FFFu + ((b >> 16) & 1u)) >> 16);  // RNE
}
__device__ __forceinline__ void cvt8_f32(const float* __restrict__ p, unsigned short* d) {
    float4 lo = *(const float4*)p, hi = *(const float4*)(p + 4);
    d[0] = f2b(lo.x); d[1] = f2b(lo.y); d[2] = f2b(lo.z); d[3] = f2b(lo.w);
    d[4] = f2b(hi.x); d[5] = f2b(hi.y); d[6] = f2b(hi.z); d[7] = f2b(hi.w);
}

// ---------------------------------------------------------------------------
// fp32 -> bf16 flat convert (n8 = count of 8-element chunks)
// ---------------------------------------------------------------------------
__global__ __launch_bounds__(256) void k_cvt(const float* __restrict__ in,
                                             unsigned short* __restrict__ out, int n8) {
    int c = blockIdx.x * 256 + threadIdx.x;
    if (c < n8) {
        unsigned short t[8];
        cvt8_f32(in + (size_t)c * 8, t);
        *(uint4*)(out + (size_t)c * 8) = *(const uint4*)t;
    }
}

// ---------------------------------------------------------------------------
// Weight transpose+convert: W (2048 x N fp32, row-major) -> WT (N x 2048 bf16)
// ---------------------------------------------------------------------------
__global__ __launch_bounds__(256) void k_wt(const float* __restrict__ W,
                                            unsigned short* __restrict__ WT, int N) {
    __shared__ alignas(16) unsigned short tile[64][72];
    int r0 = blockIdx.y * 64, c0 = blockIdx.x * 64;
    int tid = threadIdx.x;
    for (int i = 0; i < 2; ++i) {
        int c = tid + i * 256;
        int row = c >> 3, c8 = (c & 7) * 8;
        unsigned short t[8];
        cvt8_f32(W + (size_t)(r0 + row) * N + c0 + c8, t);
        *(uint4*)&tile[row][c8] = *(const uint4*)t;
    }
    __syncthreads();
    for (int i = 0; i < 2; ++i) {
        int c = tid + i * 256;
        int col = c >> 3, r8 = (c & 7) * 8;
        unsigned short t[8];
        for (int j = 0; j < 8; ++j) t[j] = tile[r8 + j][col];
        *(uint4*)(WT + (size_t)(c0 + col) * 2048 + r0 + r8) = *(const uint4*)t;
    }
}

// ---------------------------------------------------------------------------
// V transpose: QKV (8192 x 3072 bf16, V = cols 2560..3071) -> VbT (512 x 8192)
// ---------------------------------------------------------------------------
__global__ __launch_bounds__(256) void k_vt(const unsigned short* __restrict__ QKV,
                                            unsigned short* __restrict__ VbT) {
    __shared__ alignas(16) unsigned short tile[64][72];
    int r0 = blockIdx.y * 64, c0 = blockIdx.x * 64;
    int tid = threadIdx.x;
    for (int i = 0; i < 2; ++i) {
        int c = tid + i * 256;
        int row = c >> 3, c8 = (c & 7) * 8;
        *(uint4*)&tile[row][c8] =
            *(const uint4*)(QKV + (size_t)(r0 + row) * 3072 + 2560 + c0 + c8);
    }
    __syncthreads();
    for (int i = 0; i < 2; ++i) {
        int c = tid + i * 256;
        int col = c >> 3, r8 = (c & 7) * 8;
        unsigned short t[8];
        for (int j = 0; j < 8; ++j) t[j] = tile[r8 + j][col];
        *(uint4*)(VbT + (size_t)(c0 + col) * 8192 + r0 + r8) = *(const uint4*)t;
    }
}

// ---------------------------------------------------------------------------
// m97-style GEMM, BK templated (32 = proven baseline; 64 = half the barrier
// drains per K at 32 KB LDS). C (MxN) = A (MxK bf16) @ Bt^T (Bt: NxK bf16).
// 128x128 tile, global_load_lds width=16 into unpadded [128][BK] with XOR
// chunk swizzle (linear LDS dest, inverse-swizzled global source, swizzled
// ds_read). Coalesced LDS-staged epilogue; outF=1 writes fp32, else bf16.
// QKV gemm runs BK=64, O-proj runs BK=32 -> within-run A/B via rocprof.
// ---------------------------------------------------------------------------
template <int BK>
__global__ __launch_bounds__(256) void k_gemm_bt(const unsigned short* __restrict__ A,
                                                 const unsigned short* __restrict__ Bt,
                                                 void* __restrict__ Cmat,
                                                 int M, int N, int K, int outF) {
    __shared__ union SM {
        struct { unsigned short A[128][BK]; unsigned short B[128][BK]; } s;
        unsigned short ct[32][136];
        float          ctf[32][136];
    } sm;
    int tid = threadIdx.x;
    int w = tid >> 6, lane = tid & 63, quad = lane >> 4, l15 = lane & 15;
    int m0 = blockIdx.y * 128, n0 = blockIdx.x * 128;
    int wm = (w >> 1) * 64, wn = (w & 1) * 64;

    facc acc[4][4];
    for (int mi = 0; mi < 4; ++mi)
        for (int ni = 0; ni < 4; ++ni)
            for (int r = 0; r < 4; ++r) acc[mi][ni][r] = 0.f;

    if constexpr (BK == 32) {
        int srow   = lane >> 2;                       // row within 16-row chunk
        int schunk = (lane & 3) ^ ((lane >> 3) & 3);  // XOR-swizzled 16B chunk
        int rslot  = (quad ^ ((l15 >> 1) & 3)) * 8;

        for (int k0 = 0; k0 < K; k0 += 32) {
            for (int j = 0; j < 2; ++j) {
                int row = w * 32 + j * 16 + srow;
                gl_lds16(A  + (size_t)(m0 + row) * K + k0 + schunk * 8, &sm.s.A[w * 32 + j * 16][0]);
                gl_lds16(Bt + (size_t)(n0 + row) * K + k0 + schunk * 8, &sm.s.B[w * 32 + j * 16][0]);
            }
            __syncthreads();
            bfrag af[4], bf[4];
            for (int mi = 0; mi < 4; ++mi) af[mi] = *(const bfrag*)&sm.s.A[wm + mi * 16 + l15][rslot];
            for (int ni = 0; ni < 4; ++ni) bf[ni] = *(const bfrag*)&sm.s.B[wn + ni * 16 + l15][rslot];
            for (int mi = 0; mi < 4; ++mi)
                for (int ni = 0; ni < 4; ++ni)
                    acc[mi][ni] = __builtin_amdgcn_mfma_f32_16x16x32_bf16(af[mi], bf[ni], acc[mi][ni], 0, 0, 0);
            __syncthreads();
        }
    } else {
        // BK = 64: rows are 128 B; 8 chunks of 16 B. Writer: issue i covers
        // rows w*32+i*8 .. +7 (lane>>3 = row offset, lane&7 = linear slot);
        // source chunk = (lane&7) ^ (lane>>3) so LDS[row][slot] holds global
        // chunk slot ^ (row&7). Reader: physical chunk = (kc*4+quad)^(row&7),
        // row&7 == l15&7 -> 8 distinct slots across lanes 0..7 => all 32
        // banks covered; lanes l and l+8 alias 1024 B apart (2-way = free).
        int srow   = lane >> 3;                       // 0..7
        int schunk = (lane & 7) ^ (lane >> 3);

        for (int k0 = 0; k0 < K; k0 += 64) {
            for (int i = 0; i < 4; ++i) {
                int row = w * 32 + i * 8;
                gl_lds16(A  + (size_t)(m0 + row + srow) * K + k0 + schunk * 8, &sm.s.A[row][0]);
                gl_lds16(Bt + (size_t)(n0 + row + srow) * K + k0 + schunk * 8, &sm.s.B[row][0]);
            }
            __syncthreads();
            bfrag af[4][2], bf[4][2];
            for (int mi = 0; mi < 4; ++mi)
                for (int kc = 0; kc < 2; ++kc)
                    af[mi][kc] = *(const bfrag*)&sm.s.A[wm + mi * 16 + l15][((kc * 4 + quad) ^ (l15 & 7)) * 8];
            for (int ni = 0; ni < 4; ++ni)
                for (int kc = 0; kc < 2; ++kc)
                    bf[ni][kc] = *(const bfrag*)&sm.s.B[wn + ni * 16 + l15][((kc * 4 + quad) ^ (l15 & 7)) * 8];
            for (int kc = 0; kc < 2; ++kc)
                for (int mi = 0; mi < 4; ++mi)
                    for (int ni = 0; ni < 4; ++ni)
                        acc[mi][ni] = __builtin_amdgcn_mfma_f32_16x16x32_bf16(af[mi][kc], bf[ni][kc], acc[mi][ni], 0, 0, 0);
            __syncthreads();
        }
    }

    // epilogue: 4 rounds; round t stages every wave's mi=t subtile (32x128)
    // then stores coalesced rows. C/D layout: col=l15, row=quad*4+r.
    for (int t = 0; t < 4; ++t) {
        __syncthreads();
        for (int ni = 0; ni < 4; ++ni)
            for (int r = 0; r < 4; ++r) {
                int lr = (w >> 1) * 16 + quad * 4 + r;
                int lc = wn + ni * 16 + l15;
                if (outF) sm.ctf[lr][lc] = acc[t][ni][r];
                else      sm.ct [lr][lc] = f2b(acc[t][ni][r]);
            }
        __syncthreads();
        if (outF) {
            for (int i = 0; i < 4; ++i) {
                int cc = tid + i * 256;
                int lr = cc >> 5, c4 = (cc & 31) * 4;
                int grow = m0 + (lr >> 4) * 64 + t * 16 + (lr & 15);
                *(float4*)((float*)Cmat + (size_t)grow * N + n0 + c4) =
                    *(const float4*)&sm.ctf[lr][c4];
            }
        } else {
            for (int i = 0; i < 2; ++i) {
                int cc = tid + i * 256;
                int lr = cc >> 4, c8 = (cc & 15) * 8;
                int grow = m0 + (lr >> 4) * 64 + t * 16 + (lr & 15);
                *(uint4*)((unsigned short*)Cmat + (size_t)grow * N + n0 + c8) =
                    *(const uint4*)&sm.ct[lr][c8];
            }
        }
    }
}

// ---------------------------------------------------------------------------
// RoPE in-place on bf16 X (8192 rows, stride elems/row, nh heads of 128).
// ---------------------------------------------------------------------------
__global__ __launch_bounds__(256) void k_rope(unsigned short* __restrict__ X,
                                              int lognh, int stride,
                                              const int* __restrict__ posPtr) {
    int tid = blockIdx.x * 256 + threadIdx.x;
    int d = tid & 63;
    int nh = 1 << lognh;
    int h = (tid >> 6) & (nh - 1);
    int row = tid >> (6 + lognh);
    int t = row & (TT - 1);
    float p = (float)(*posPtr + t);
    size_t base = (size_t)row * stride + h * 128 + d;
    union { unsigned int i; float f; } a, b2;
    a.i  = ((unsigned int)X[base]) << 16;
    b2.i = ((unsigned int)X[base + 64]) << 16;
    float x1 = a.f, x2 = b2.f;
    int i1 = d >> 1;
    float f1 = exp2f(-(float)i1 * 0.20762050595278f);
    float f2 = exp2f(-(float)(i1 + 32) * 0.20762050595278f);
    float th1 = p * f1, th2 = p * f2;
    X[base]      = f2b(x1 * cosf(th1) - x2 * sinf(th1));
    X[base + 64] = f2b(x2 * cosf(th2) + x1 * sinf(th2));
}

// ---------------------------------------------------------------------------
// Flash attention, causal, GQA (16 q / 4 kv heads). 512 threads, QBLK=128,
// paired q-tiles (i, 15-i) for perfect balance; double-buffered K/V LDS,
// one barrier per K-step, register prefetch issued post-barrier.
// VALU cuts: per-wave inactive-tile skip; wave-uniform interior-tile fast
// path (no mask cndmasks); T13 defer-max THR=8.
// ---------------------------------------------------------------------------
__device__ __forceinline__ void flash_pass(
    int qbase, int b, int h, int kvh,
    const unsigned short* __restrict__ QKV,
    const unsigned short* __restrict__ VbT,
    unsigned short* __restrict__ att,
    unsigned short (&Ks)[2][32][136],
    unsigned short (&Vt)[2][128][40],
    unsigned short (&Pt)[8][16][40]) {

    int tid = threadIdx.x;
    int w = tid >> 6, lane = tid & 63, quad = lane >> 4, l15 = lane & 15;

    bfrag qf[4];
    {
        size_t qrow = (size_t)(b * TT + qbase + w * 16 + l15);
        for (int kc = 0; kc < 4; ++kc)
            qf[kc] = *(const bfrag*)(QKV + qrow * 3072 + h * 128 + kc * 32 + quad * 8);
    }

    float mrow[4], lrow[4];
    facc o[8];
    for (int r = 0; r < 4; ++r) { mrow[r] = NEG_BIG; lrow[r] = 0.f; }
    for (int nb2 = 0; nb2 < 8; ++nb2)
        for (int r = 0; r < 4; ++r) o[nb2][r] = 0.f;

    int krow = tid >> 4, d8 = (tid & 15) * 8;   // K: row 0..31, 16B chunk
    int vd = tid >> 2, tc = (tid & 3) * 8;      // V: d 0..127, 8 t-cols
    const unsigned short* Kg = QKV + (size_t)(b * TT) * 3072 + 2048 + kvh * 128;
    const unsigned short* Vg = VbT + (size_t)(kvh * 128 + vd) * 8192 + b * TT;

    const float sc = 0.08838834764831845f;   // 1/sqrt(128)
    int kmax = qbase + 128;
    int nt = kmax >> 5;
    int qgmin = qbase + w * 16;              // smallest q-row this wave owns

    uint4 rk = *(const uint4*)(Kg + (size_t)krow * 3072 + d8);
    uint4 rv = *(const uint4*)(Vg + tc);

    for (int t = 0; t < nt; ++t) {
        int cur = t & 1;
        int k0 = t * 32;
        *(uint4*)&Ks[cur][krow][d8] = rk;
        *(uint4*)&Vt[cur][vd][tc]   = rv;
        __syncthreads();

        if (t + 1 < nt) {
            int k0n = k0 + 32;
            rk = *(const uint4*)(Kg + (size_t)(k0n + krow) * 3072 + d8);
            rv = *(const uint4*)(Vg + k0n + tc);
        }

        // tiles entirely above this wave's rows contribute nothing: skip
        // compute (barrier at loop top stays uniform across waves).
        if (k0 > qgmin + 15) continue;

        facc s[2];
        for (int nb = 0; nb < 2; ++nb) {
            for (int r = 0; r < 4; ++r) s[nb][r] = 0.f;
            for (int kc = 0; kc < 4; ++kc) {
                bfrag kf = *(const bfrag*)&Ks[cur][nb * 16 + l15][kc * 32 + quad * 8];
                s[nb] = __builtin_amdgcn_mfma_f32_16x16x32_bf16(qf[kc], kf, s[nb], 0, 0, 0);
            }
        }

        bool fullT = (k0 + 31) <= qgmin;     // wave-uniform: no masking needed
        float alpha[4];
        int growAny = 0;
        for (int r = 0; r < 4; ++r) {
            float v0, v1;
            if (fullT) {
                v0 = s[0][r] * sc;
                v1 = s[1][r] * sc;
            } else {
                int qg = qgmin + quad * 4 + r;
                v0 = (k0 + l15 > qg)      ? NEG_BIG : s[0][r] * sc;
                v1 = (k0 + 16 + l15 > qg) ? NEG_BIG : s[1][r] * sc;
            }
            float mx = fmaxf(v0, v1);
            for (int off = 1; off < 16; off <<= 1) mx = fmaxf(mx, __shfl_xor(mx, off, 64));
            bool need = (mx > mrow[r] + 8.f);     // T13 defer-max, THR=8
            float mnew = need ? mx : mrow[r];
            growAny |= need;
            alpha[r] = need ? __expf(mrow[r] - mnew) : 1.f;
            float p0 = __expf(v0 - mnew);         // exp(-huge)=0 for masked lanes
            float p1 = __expf(v1 - mnew);
            float psum = p0 + p1;
            for (int off = 1; off < 16; off <<= 1) psum += __shfl_xor(psum, off, 64);
            lrow[r] = lrow[r] * alpha[r] + psum;
            mrow[r] = mnew;
            Pt[w][quad * 4 + r][l15]      = f2b(p0);
            Pt[w][quad * 4 + r][16 + l15] = f2b(p1);
        }
        if (__any(growAny)) {
            for (int nb2 = 0; nb2 < 8; ++nb2)
                for (int r = 0; r < 4; ++r) o[nb2][r] *= alpha[r];
        }

        asm volatile("s_waitcnt lgkmcnt(0)" ::: "memory");   // wave-local RAW on Pt[w]
        bfrag pf = *(const bfrag*)&Pt[w][l15][quad * 8];
        for (int nb2 = 0; nb2 < 8; ++nb2) {
            bfrag vf = *(const bfrag*)&Vt[cur][nb2 * 16 + l15][quad * 8];
            o[nb2] = __builtin_amdgcn_mfma_f32_16x16x32_bf16(pf, vf, o[nb2], 0, 0, 0);
        }
    }

    for (int nb2 = 0; nb2 < 8; ++nb2)
        for (int r = 0; r < 4; ++r) {
            int qg = qbase + w * 16 + quad * 4 + r;
            att[(size_t)(b * TT + qg) * 2048 + h * 128 + nb2 * 16 + l15] =
                f2b(o[nb2][r] / lrow[r]);
        }
}

__global__ __launch_bounds__(512, 4) void k_flash(const unsigned short* __restrict__ QKV,
                                                  const unsigned short* __restrict__ VbT,
                                                  unsigned short* __restrict__ att) {
    __shared__ alignas(16) unsigned short Ks[2][32][136];
    __shared__ alignas(16) unsigned short Vt[2][128][40];
    __shared__ alignas(16) unsigned short Pt[8][16][40];
    int bh = blockIdx.y;
    int b = bh >> 4, h = bh & 15;
    int kvh = h >> 2;
    int i = blockIdx.x;

    flash_pass(i * 128, b, h, kvh, QKV, VbT, att, Ks, Vt, Pt);
    __syncthreads();
    flash_pass((15 - i) * 128, b, h, kvh, QKV, VbT, att, Ks, Vt, Pt);
}

// ---------------------------------------------------------------------------
extern "C" void kernel_launch(void* const* d_in, const int* in_sizes, int n_in,
                              void* d_out, int out_size, void* d_ws, size_t ws_size,
                              hipStream_t stream) {
    const float* x  = (const float*)d_in[0];
    const float* Wq = (const float*)d_in[1];
    const float* Wk = (const float*)d_in[2];
    const float* Wv = (const float*)d_in[3];
    const float* Wo = (const float*)d_in[4];
    const int* pos  = (const int*)d_in[5];

    char* ws = (char*)d_ws;
    unsigned short* xb   = (unsigned short*)(ws + 0);          // 32 MB (8192x2048); reused as att out
    unsigned short* QKV  = (unsigned short*)(ws + 33554432);   // 48 MB (8192x3072)
    unsigned short* VbT  = (unsigned short*)(ws + 83886080);   //  8 MB (512x8192)
    unsigned short* WqT  = (unsigned short*)(ws + 92274688);   //  8 MB (2048x2048)
    unsigned short* WkvT = (unsigned short*)(ws + 100663296);  //  4 MB (1024x2048) -- contiguous with WqT
    unsigned short* WoT  = (unsigned short*)(ws + 104857600);  //  8 MB -> 108 MB total

    // bf16 conversion + weight transposes (WqT|WkvT form one contiguous 3072x2048 Bt)
    k_cvt<<<8192, 256, 0, stream>>>(x, xb, 2097152);
    k_wt<<<dim3(32, 32), 256, 0, stream>>>(Wq, WqT, 2048);
    k_wt<<<dim3(8, 32),  256, 0, stream>>>(Wk, WkvT, 512);
    k_wt<<<dim3(8, 32),  256, 0, stream>>>(Wv, WkvT + (size_t)512 * 2048, 512);
    k_wt<<<dim3(32, 32), 256, 0, stream>>>(Wo, WoT, 2048);

    // fused Q|K|V projection (BK=64 arm of the A/B)
    k_gemm_bt<64><<<dim3(24, 64), 256, 0, stream>>>(xb, WqT, QKV, 8192, 3072, 2048, 0);

    // RoPE (Q: 16 heads, cols 0..2047; K: 4 heads, cols 2048..2559; stride 3072)
    k_rope<<<32768, 256, 0, stream>>>(QKV, 4, 3072, pos);
    k_rope<<<8192,  256, 0, stream>>>(QKV + 2048, 2, 3072, pos);

    // V transpose for flash B-frag staging
    k_vt<<<dim3(8, 128), 256, 0, stream>>>(QKV, VbT);

    // causal GQA flash attention -> xb (x no longer needed)
    k_flash<<<dim3(8, 64), 512, 0, stream>>>(QKV, VbT, xb);

    // output projection -> fp32 d_out (BK=32 arm of the A/B)
    k_gemm_bt<32><<<dim3(16, 64), 256, 0, stream>>>(xb, WoT, d_out, 8192, 2048, 2048, 1);
}